// Round 7
// baseline (126.879 us; speedup 1.0000x reference)
//
#include <hip/hip_runtime.h>

// LIF neuron bank: B=16, N=2048, T=1000. Sequential scan in T per neuron.
//
// R6: 512B-contiguous store segments. Evidence: effective BW tracks store
// segment size (16B scattered = 2.3 TB/s (R1), 256B = 3.3 (R4), 1KB fill =
// 7.0). To double segment size without doubling LDS: spikes are bit-packed
// by the compute wave (2 u32 per 64 steps per lane, off the serial chain);
// only v is staged as floats. LDS = v ring[4 quarters x 64 steps] (64KB) +
// bits ring (2KB) = 66KB -> 2 blocks/CU.
//   wave 0 (compute): register-prefetched u loads (R4's proven path),
//     64 LIF steps/phase, v float4 -> swizzled ring, s -> bit pack.
//   wave 1 (v-storer): on even phases stores a 128-step macro (2 quarters):
//     inst k = rows 2k,2k+1, each half-wave writes 512B contiguous.
//   wave 2 (s-storer): same addressing, expands bits -> exact 1.0f/0.0f.
// Barriers are LDS-only (lgkmcnt); global stores never drained in-loop.
// Tail: q14 (t 896..959) via 256B pattern, q15 (t 960..999) scattered.
//
// FP discipline: reference does NOT contract mul+add into FMA; use
// __fmul_rn/__fadd_rn/__fsub_rn to stay bit-exact (R0-R5: absmax 0.0).

constexpr int B_ = 16;
constexpr int N_ = 2048;
constexpr int T_ = 1000;
constexpr int Q = 64;                  // steps per quarter (= per phase)
constexpr int QF4 = Q / 4;             // 16 float4 per quarter
constexpr int NPH = 16;                // phases 0..15 (15 full + 40-step tail)
constexpr int TAIL_F4 = 10;            // phase 15: 40 steps

// LDS-ordering barrier (no vmcnt drain: stores stay in flight).
#define LDS_BARRIER()                                          \
    do {                                                       \
        asm volatile("s_waitcnt lgkmcnt(0)" ::: "memory");     \
        __builtin_amdgcn_s_barrier();                          \
        __builtin_amdgcn_sched_barrier(0);                     \
    } while (0)

__global__ __launch_bounds__(192) void lif_kernel(
    const float* __restrict__ u,          // (B, N, T)
    const float* __restrict__ theta_base, // (1, N, 1) -> N floats
    float* __restrict__ spikes,           // (B, N, T)
    float* __restrict__ vhist)            // (B, N, T)
{
    __shared__ float4 v_ring[4][64][QF4];   // 64 KiB: [buf][row][slot]
    __shared__ uint2  s_bits[4][64];        //  2 KiB: 64 spike bits/row/quarter

    const int lane = threadIdx.x & 63;
    const int wid = threadIdx.x >> 6;
    const int blk0 = blockIdx.x * 64;       // first neuron of block

    if (wid == 0) {
        // ---------------- compute wave ----------------
        const float tb = theta_base[(blk0 + lane) & (N_ - 1)];
        const float c5 = __fmul_rn(tb, 0.005f);   // tb * (1-0.995) rounded
        float v = 0.0f, theta = tb, ref = 0.0f;
        const float* up = u + (size_t)(blk0 + lane) * T_;
        const int swz = lane & 15;

        float4 bufA[QF4], bufB[QF4];   // named bufs: static indexing only

        auto load_q = [&](float4 (&b)[QF4], int t0) {
#pragma unroll
            for (int i = 0; i < QF4; ++i)
                b[i] = *reinterpret_cast<const float4*>(up + t0 + 4 * i);
        };
        auto load_tail = [&](float4 (&b)[QF4]) {
#pragma unroll
            for (int i = 0; i < TAIL_F4; ++i)
                b[i] = *reinterpret_cast<const float4*>(up + 15 * Q + 4 * i);
        };

        // 4 LIF steps; spike bits go to bw at (sh+k); returns v float4.
        auto stepf4 = [&](const float4 u4, unsigned& bw, int sh) -> float4 {
            const float uin[4] = {u4.x, u4.y, u4.z, u4.w};
            float vo[4];
#pragma unroll
            for (int k = 0; k < 4; ++k) {
                // u_eff = u_t * (1 - (ref>0))
                const float ueff = (ref > 0.0f) ? 0.0f : uin[k];
                // v = 0.95*v + u_eff   (separate mul/add, no FMA)
                v = __fadd_rn(__fmul_rn(0.95f, v), ueff);
                // s = (v - theta >= 0)
                const float d = __fsub_rn(v, theta);
                const bool s = (d >= 0.0f);
                // v -= s*theta
                v = s ? __fsub_rn(v, theta) : v;
                // ref = max(ref-1,0); if (s) ref = 2
                ref = fmaxf(__fsub_rn(ref, 1.0f), 0.0f);
                ref = s ? 2.0f : ref;
                // theta = theta*0.995 + tb*0.005 + 0.35*s
                theta = __fadd_rn(__fmul_rn(theta, 0.995f), c5);
                theta = s ? __fadd_rn(theta, 0.35f) : theta;

                bw |= (s ? 1u : 0u) << (sh + k);   // off the serial chain
                vo[k] = v;
            }
            return make_float4(vo[0], vo[1], vo[2], vo[3]);
        };

        auto process_q = [&](const float4 (&b)[QF4], int bq) {
            unsigned blo = 0, bhi = 0;
#pragma unroll
            for (int tf = 0; tf < QF4; ++tf) {
                float4 v4 = (tf < 8) ? stepf4(b[tf], blo, 4 * tf)
                                     : stepf4(b[tf], bhi, 4 * (tf - 8));
                v_ring[bq][lane][tf ^ swz] = v4;
            }
            s_bits[bq][lane] = make_uint2(blo, bhi);
        };
        auto process_tail = [&](const float4 (&b)[QF4], int bq) {
            unsigned blo = 0, bhi = 0;
#pragma unroll
            for (int tf = 0; tf < TAIL_F4; ++tf) {
                float4 v4 = (tf < 8) ? stepf4(b[tf], blo, 4 * tf)
                                     : stepf4(b[tf], bhi, 4 * (tf - 8));
                v_ring[bq][lane][tf ^ swz] = v4;
            }
            s_bits[bq][lane] = make_uint2(blo, bhi);
        };

        load_q(bufA, 0);
#pragma unroll 1
        for (int p = 0; p < NPH; ++p) {
            if (!(p & 1)) {                      // even: process A, load B
                if (p < 14) load_q(bufB, (p + 1) * Q);
                else if (p == 14) load_tail(bufB);
                process_q(bufA, p & 3);
            } else {                             // odd: process B, load A
                if (p < 15) {
                    load_q(bufA, (p + 1) * Q);
                    process_q(bufB, p & 3);
                } else {
                    process_tail(bufB, 3);       // phase 15: 40 steps
                }
            }
            LDS_BARRIER();
        }
    } else if (wid == 1) {
        // ---------------- v-storer ----------------
        float* gv = vhist + (size_t)blk0 * T_;
        const int jj = lane & 31;
        const int half = lane >> 5;

#pragma unroll 1
        for (int p = 0; p < NPH; ++p) {
            if (p >= 2 && !(p & 1)) {            // p = 2,4,...,14
                const int t0 = (p - 2) * Q;      // macro start (steps)
                const int b0 = (p - 2) & 3;
                const int bq = (b0 + (jj >> 4)) & 3;
                const int slb = jj & 15;
#pragma unroll
                for (int k = 0; k < 32; ++k) {
                    const int R = 2 * k + half;
                    const float4 w = v_ring[bq][R][slb ^ (R & 15)];
                    *(float4*)(gv + (size_t)R * T_ + t0 + 4 * jj) = w;
                }
            }
            LDS_BARRIER();
        }
        // epilogue: q14 (t 896..959) 256B pattern from ring[2]
        {
            const int r0 = lane >> 4, tf = lane & 15;
#pragma unroll
            for (int k = 0; k < 16; ++k) {
                const int R = 4 * k + r0;
                const float4 w = v_ring[2][R][tf ^ (R & 15)];
                *(float4*)(gv + (size_t)R * T_ + 14 * Q + 4 * tf) = w;
            }
        }
        // q15 (t 960..999) scattered per-lane from ring[3]
        {
#pragma unroll
            for (int tf = 0; tf < TAIL_F4; ++tf) {
                const float4 w = v_ring[3][lane][tf ^ (lane & 15)];
                *(float4*)(gv + (size_t)lane * T_ + 15 * Q + 4 * tf) = w;
            }
        }
    } else {
        // ---------------- s-storer (expand bits -> 0.0f/1.0f) ----------------
        float* gs = spikes + (size_t)blk0 * T_;
        const int jj = lane & 31;
        const int half = lane >> 5;

        auto expand = [](unsigned w, int ob) -> float4 {
            float4 f;
            f.x = ((w >> (ob + 0)) & 1u) ? 1.0f : 0.0f;
            f.y = ((w >> (ob + 1)) & 1u) ? 1.0f : 0.0f;
            f.z = ((w >> (ob + 2)) & 1u) ? 1.0f : 0.0f;
            f.w = ((w >> (ob + 3)) & 1u) ? 1.0f : 0.0f;
            return f;
        };

#pragma unroll 1
        for (int p = 0; p < NPH; ++p) {
            if (p >= 2 && !(p & 1)) {
                const int t0 = (p - 2) * Q;
                const int b0 = (p - 2) & 3;
                const int bq = (b0 + (jj >> 4)) & 3;
                const int wq = (jj & 15) >> 3;
                const int ob = 4 * (jj & 7);
#pragma unroll
                for (int k = 0; k < 32; ++k) {
                    const int R = 2 * k + half;
                    const uint2 bw = s_bits[bq][R];
                    const unsigned w = wq ? bw.y : bw.x;
                    *(float4*)(gs + (size_t)R * T_ + t0 + 4 * jj) =
                        expand(w, ob);
                }
            }
            LDS_BARRIER();
        }
        // epilogue: q14 256B pattern from bits[2]
        {
            const int r0 = lane >> 4, tf = lane & 15;
            const int wq = tf >> 3;
            const int ob = 4 * (tf & 7);
#pragma unroll
            for (int k = 0; k < 16; ++k) {
                const int R = 4 * k + r0;
                const uint2 bw = s_bits[2][R];
                const unsigned w = wq ? bw.y : bw.x;
                *(float4*)(gs + (size_t)R * T_ + 14 * Q + 4 * tf) =
                    expand(w, ob);
            }
        }
        // q15 scattered per-lane from bits[3]
        {
            const uint2 bw = s_bits[3][lane];
#pragma unroll
            for (int tf = 0; tf < TAIL_F4; ++tf) {
                const unsigned w = (tf >> 3) ? bw.y : bw.x;
                *(float4*)(gs + (size_t)lane * T_ + 15 * Q + 4 * tf) =
                    expand(w, 4 * (tf & 7));
            }
        }
    }
}

extern "C" void kernel_launch(void* const* d_in, const int* in_sizes, int n_in,
                              void* d_out, int out_size, void* d_ws, size_t ws_size,
                              hipStream_t stream) {
    const float* u = (const float*)d_in[0];           // (B,N,T)
    const float* theta_base = (const float*)d_in[1];  // (1,N,1)
    float* out = (float*)d_out;
    float* spikes = out;                               // first output
    float* vhist = out + (size_t)B_ * N_ * T_;         // second output

    const int grid = (B_ * N_) / 64;   // 512 blocks (64 neurons each)
    lif_kernel<<<grid, 192, 0, stream>>>(u, theta_base, spikes, vhist);
}